// Round 12
// baseline (599.532 us; speedup 1.0000x reference)
//
#include <hip/hip_runtime.h>
#include <hip/hip_bf16.h>
#include <cstdint>

#define N_NODES 100000
#define N_EDGES 1600000
#define N_GRAPHS 2000
#define IN_DIM 37
#define HID 128

#define GEMM_GRID 1563      // 64-node tiles
#define HIST_BLOCKS 6250    // 1.6M / 256
#define PACK67_BLOCKS 384   // 6*16384/256 (m=3..8)
#define PREPACK_BLOCKS 96   // 3*8192/256  (m=0..2)
#define P1_BLOCKS 8336      // 2084*4 interleaved: 3/4 hist, 1/4 gemm0+pack

typedef __attribute__((ext_vector_type(8))) short short8;
typedef __attribute__((ext_vector_type(4))) float f32x4;

static __device__ __forceinline__ short bf16_bits(float f) {
    __hip_bfloat16 h = __float2bfloat16(f);
    return *reinterpret_cast<short*>(&h);
}
static __device__ __forceinline__ float bf16_lo(uint32_t u) {
    uint32_t v = u << 16;
    return *reinterpret_cast<float*>(&v);
}
static __device__ __forceinline__ float bf16_hi(uint32_t u) {
    uint32_t v = u & 0xffff0000u;
    return *reinterpret_cast<float*>(&v);
}
static __device__ __forceinline__ uint32_t pack_bf16(float lo, float hi) {
    return ((uint32_t)(uint16_t)bf16_bits(hi) << 16) | (uint16_t)bf16_bits(lo);
}

// ---------------- weight pack ----------------

struct PackArgs {
    const float* w[9];
    short* o[9];
};

static __device__ __forceinline__ void pack_one(const PackArgs& pa, int m, int r, int kin) {
    const int i = r & 7, lane = (r >> 3) & 63, t = (r >> 9) & 7, kb = r >> 12;
    const int k = kb * 32 + (lane >> 4) * 8 + i;
    const int c = t * 16 + (lane & 15);
    float v = (k < kin) ? pa.w[m][(size_t)k * HID + c] : 0.f;
    pa.o[m][r] = bf16_bits(v);
}

__global__ __launch_bounds__(256) void prepack_kernel(PackArgs pa) {
    const int idx = blockIdx.x * 256 + threadIdx.x;  // < 24576
    pack_one(pa, idx >> 13, idx & 8191, IN_DIM);
}

// ---------------- layer-0 GEMM from fp32 x (K=64 padded), non-swapped ----------------
// D0 = bf16(x@W1 + b1), E0 = bf16(x@W3 + b3), Bb = bf16(x@W2)

static __device__ __forceinline__ void gemm0_body(
    int blk, const float* __restrict__ x,
    const short* __restrict__ Wp1, const short* __restrict__ Wp2, const short* __restrict__ Wp3,
    const float* __restrict__ b1v, const float* __restrict__ b3v,
    short* __restrict__ D0, short* __restrict__ E0, short* __restrict__ Bb) {
    const int tid = threadIdx.x;
    const int wave = tid >> 6, lane = tid & 63;
    const int row_base = blk * 64 + wave * 16;
    const int r15 = lane & 15, kg = lane >> 4;
    int arow = row_base + r15;
    if (arow >= N_NODES) arow = N_NODES - 1;
    const float* xr = x + (size_t)arow * IN_DIM;

    f32x4 acc1[8], acc2[8], acc3[8];
    #pragma unroll
    for (int t = 0; t < 8; t++) {
        acc1[t] = (f32x4)0.f; acc2[t] = (f32x4)0.f; acc3[t] = (f32x4)0.f;
    }
    #pragma unroll
    for (int kb = 0; kb < 2; kb++) {
        short8 av;
        #pragma unroll
        for (int i = 0; i < 8; i++) {
            const int k = kb * 32 + kg * 8 + i;
            av[i] = (k < IN_DIM) ? bf16_bits(xr[k]) : (short)0;
        }
        #pragma unroll
        for (int t = 0; t < 8; t++) {
            const int widx = (kb * 8 + t) * 512 + lane * 8;
            short8 w1 = *(const short8*)(Wp1 + widx);
            short8 w2 = *(const short8*)(Wp2 + widx);
            short8 w3 = *(const short8*)(Wp3 + widx);
            acc1[t] = __builtin_amdgcn_mfma_f32_16x16x32_bf16(av, w1, acc1[t], 0, 0, 0);
            acc2[t] = __builtin_amdgcn_mfma_f32_16x16x32_bf16(av, w2, acc2[t], 0, 0, 0);
            acc3[t] = __builtin_amdgcn_mfma_f32_16x16x32_bf16(av, w3, acc3[t], 0, 0, 0);
        }
    }
    int grow[4]; bool ok[4];
    #pragma unroll
    for (int i = 0; i < 4; i++) {
        grow[i] = row_base + kg * 4 + i;
        ok[i] = grow[i] < N_NODES;
    }
    #pragma unroll
    for (int t = 0; t < 8; t++) {
        const int c = t * 16 + r15;
        const float bb1 = b1v[c], bb3 = b3v[c];
        #pragma unroll
        for (int i = 0; i < 4; i++) {
            if (ok[i]) {
                size_t o = (size_t)grow[i] * HID + c;
                D0[o] = bf16_bits(acc1[t][i] + bb1);
                E0[o] = bf16_bits(acc3[t][i] + bb3);
                Bb[o] = bf16_bits(acc2[t][i]);
            }
        }
    }
}

// ---------------- phase 1 (interleaved): hist+rank (3/4) || gemm0 + pack m3..8 (1/4) ----------------

struct P1Args {
    const float* x;
    const int* ei;
    int* cnt; int* rank;
    const short* Wp1; const short* Wp2; const short* Wp3;
    const float* b1; const float* b3;
    short* D0; short* E0; short* Bb;
    PackArgs pa;
};

__global__ __launch_bounds__(256) void phase1_kernel(P1Args a) {
    const int b = blockIdx.x;
    const int q = b >> 2, r = b & 3;
    if (r != 0) {
        const int eb = q * 3 + (r - 1);
        if (eb >= HIST_BLOCKS) return;
        const int e = eb * 256 + threadIdx.x;
        const int d = a.ei[N_EDGES + e];
        a.rank[e] = atomicAdd(&a.cnt[d], 1);    // the ONLY atomic pass; no dependent scatter
        return;
    }
    if (q < GEMM_GRID) {
        gemm0_body(q, a.x, a.Wp1, a.Wp2, a.Wp3, a.b1, a.b3, a.D0, a.E0, a.Bb);
        return;
    }
    const int pb = q - GEMM_GRID;
    if (pb < PACK67_BLOCKS) {
        const int idx = pb * 256 + threadIdx.x;  // < 98304
        pack_one(a.pa, 3 + (idx >> 14), idx & 16383, HID);
    }
}

// ---------------- scan: cnt -> rowptr (+degf) ----------------

__global__ __launch_bounds__(1024) void scan_blocks(const int* __restrict__ cnt,
                                                    int* __restrict__ partial,
                                                    int* __restrict__ bsum) {
    __shared__ int ws[16];
    const int tid = threadIdx.x, lane = tid & 63, wv = tid >> 6;
    const int i = blockIdx.x * 1024 + tid;
    int v0 = (i < N_NODES) ? cnt[i] : 0;
    int v = v0;
    #pragma unroll
    for (int off = 1; off < 64; off <<= 1) {
        int n = __shfl_up(v, off, 64);
        if (lane >= off) v += n;
    }
    if (lane == 63) ws[wv] = v;
    __syncthreads();
    int woff = 0, tot = 0;
    #pragma unroll
    for (int w = 0; w < 16; w++) {
        int s = ws[w];
        if (w < wv) woff += s;
        tot += s;
    }
    if (i < N_NODES) partial[i] = woff + v - v0;
    if (tid == 0) bsum[blockIdx.x] = tot;
}

__global__ __launch_bounds__(1024) void scan_finalize(const int* __restrict__ partial,
                                                      const int* __restrict__ bsum,
                                                      const int* __restrict__ cnt,
                                                      int* __restrict__ rowptr,
                                                      float* __restrict__ degf) {
    __shared__ int off_s;
    const int tid = threadIdx.x, b = blockIdx.x;
    if (tid < 64) {
        int acc = 0;
        for (int j = tid; j < b; j += 64) acc += bsum[j];
        #pragma unroll
        for (int off = 32; off; off >>= 1) acc += __shfl_down(acc, off, 64);
        if (tid == 0) off_s = acc;
    }
    __syncthreads();
    const int i = b * 1024 + tid;
    if (i < N_NODES) {
        rowptr[i] = off_s + partial[i];
        degf[i] = (float)cnt[i];
    }
    if (b == 0 && tid == 0) rowptr[N_NODES] = N_EDGES;
}

// ---------------- fill: scatter col (no atomics) ----------------

__global__ __launch_bounds__(256) void fill_kernel(const int* __restrict__ ei,
                                                   const int* __restrict__ rank,
                                                   const int* __restrict__ rowptr,
                                                   int* __restrict__ col) {
    const int e = blockIdx.x * 256 + threadIdx.x;
    const int s = ei[e];
    const int d = ei[N_EDGES + e];
    col[rowptr[d] + rank[e]] = s;
}

// ---------------- gather core: 4 edges/wave-iter, 16B/lane, col prefetch+shuffle ----------------

static __device__ __forceinline__ void agg_edges4(const int* __restrict__ col, int s, int e,
                                                  const short* __restrict__ Bb,
                                                  int lane, int grp, int l16, float* acc) {
    for (int base = s; base < e; base += 64) {
        const int cnt = min(64, e - base);
        const int ci = base + lane;
        const int cv = col[(ci < e) ? ci : (e - 1)];
        for (int t = 0; t < cnt; t += 4) {
            const int idx = t + grp;
            const bool on = idx < cnt;
            const float w = on ? 1.f : 0.f;
            const int c = __shfl(cv, on ? idx : 0, 64);
            const uint4 u = *(const uint4*)(Bb + (size_t)c * HID + l16 * 8);
            acc[0] = fmaf(w, bf16_lo(u.x), acc[0]);
            acc[1] = fmaf(w, bf16_hi(u.x), acc[1]);
            acc[2] = fmaf(w, bf16_lo(u.y), acc[2]);
            acc[3] = fmaf(w, bf16_hi(u.y), acc[3]);
            acc[4] = fmaf(w, bf16_lo(u.z), acc[4]);
            acc[5] = fmaf(w, bf16_hi(u.z), acc[5]);
            acc[6] = fmaf(w, bf16_lo(u.w), acc[6]);
            acc[7] = fmaf(w, bf16_hi(u.w), acc[7]);
        }
    }
    #pragma unroll
    for (int j = 0; j < 8; j++) {
        acc[j] += __shfl_xor(acc[j], 16, 64);
        acc[j] += __shfl_xor(acc[j], 32, 64);
    }
}

// layer-0 gather: Hb = bf16(relu(deg*D0 - agg + E0))
__global__ __launch_bounds__(256) void gather0_kernel(const int* __restrict__ rowptr,
                                                      const int* __restrict__ col,
                                                      const short* __restrict__ Bb,
                                                      const short* __restrict__ D0,
                                                      const short* __restrict__ E0,
                                                      short* __restrict__ Hb) {
    const int wid = (blockIdx.x * 256 + threadIdx.x) >> 6;
    if (wid >= N_NODES) return;
    const int lane = threadIdx.x & 63, grp = lane >> 4, l16 = lane & 15;
    const int s = rowptr[wid], e = rowptr[wid + 1];
    float acc[8] = {0.f, 0.f, 0.f, 0.f, 0.f, 0.f, 0.f, 0.f};
    agg_edges4(col, s, e, Bb, lane, grp, l16, acc);
    if (grp == 0) {
        const float dg = (float)(e - s);
        const uint4 ud = *(const uint4*)(D0 + (size_t)wid * HID + l16 * 8);
        const uint4 ue = *(const uint4*)(E0 + (size_t)wid * HID + l16 * 8);
        uint4 r;
        r.x = pack_bf16(fmaxf(fmaf(dg, bf16_lo(ud.x), bf16_lo(ue.x)) - acc[0], 0.f),
                        fmaxf(fmaf(dg, bf16_hi(ud.x), bf16_hi(ue.x)) - acc[1], 0.f));
        r.y = pack_bf16(fmaxf(fmaf(dg, bf16_lo(ud.y), bf16_lo(ue.y)) - acc[2], 0.f),
                        fmaxf(fmaf(dg, bf16_hi(ud.y), bf16_hi(ue.y)) - acc[3], 0.f));
        r.z = pack_bf16(fmaxf(fmaf(dg, bf16_lo(ud.z), bf16_lo(ue.z)) - acc[4], 0.f),
                        fmaxf(fmaf(dg, bf16_hi(ud.z), bf16_hi(ue.z)) - acc[5], 0.f));
        r.w = pack_bf16(fmaxf(fmaf(dg, bf16_lo(ud.w), bf16_lo(ue.w)) - acc[6], 0.f),
                        fmaxf(fmaf(dg, bf16_hi(ud.w), bf16_hi(ue.w)) - acc[7], 0.f));
        *(uint4*)(Hb + (size_t)wid * HID + l16 * 8) = r;
    }
}

// layers 1/2 gather: Hb = bf16(relu(OUT - agg)), deg applied in gemm
__global__ __launch_bounds__(256) void gatherL_kernel(const int* __restrict__ rowptr,
                                                      const int* __restrict__ col,
                                                      const short* __restrict__ Bb,
                                                      const short* __restrict__ OUTb,
                                                      short* __restrict__ Hb) {
    const int wid = (blockIdx.x * 256 + threadIdx.x) >> 6;
    if (wid >= N_NODES) return;
    const int lane = threadIdx.x & 63, grp = lane >> 4, l16 = lane & 15;
    const int s = rowptr[wid], e = rowptr[wid + 1];
    float acc[8] = {0.f, 0.f, 0.f, 0.f, 0.f, 0.f, 0.f, 0.f};
    agg_edges4(col, s, e, Bb, lane, grp, l16, acc);
    if (grp == 0) {
        const uint4 uo = *(const uint4*)(OUTb + (size_t)wid * HID + l16 * 8);
        uint4 r;
        r.x = pack_bf16(fmaxf(bf16_lo(uo.x) - acc[0], 0.f), fmaxf(bf16_hi(uo.x) - acc[1], 0.f));
        r.y = pack_bf16(fmaxf(bf16_lo(uo.y) - acc[2], 0.f), fmaxf(bf16_hi(uo.y) - acc[3], 0.f));
        r.z = pack_bf16(fmaxf(bf16_lo(uo.z) - acc[4], 0.f), fmaxf(bf16_hi(uo.z) - acc[5], 0.f));
        r.w = pack_bf16(fmaxf(bf16_lo(uo.w) - acc[6], 0.f), fmaxf(bf16_hi(uo.w) - acc[7], 0.f));
        *(uint4*)(Hb + (size_t)wid * HID + l16 * 8) = r;
    }
}

// ---------------- layers 1/2 GEMM (non-swapped): OUT = bf16(deg*(h@W1+b1)+h@W3+b3), Bb = bf16(h@W2) ----------------

__global__ __launch_bounds__(256) void leconv_mfma(
    const short* __restrict__ Hb,
    const short* __restrict__ Wp1, const short* __restrict__ Wp2, const short* __restrict__ Wp3,
    const float* __restrict__ b1v, const float* __restrict__ b3v,
    const float* __restrict__ degf,
    short* __restrict__ Bb, short* __restrict__ OUTb) {
    const int tid = threadIdx.x;
    const int wave = tid >> 6, lane = tid & 63;
    const int row_base = blockIdx.x * 64 + wave * 16;
    const int r15 = lane & 15, kg = lane >> 4;
    int arow = row_base + r15;
    if (arow >= N_NODES) arow = N_NODES - 1;
    const short* aptr = Hb + (size_t)arow * HID + kg * 8;

    f32x4 acc1[8], acc2[8], acc3[8];
    #pragma unroll
    for (int t = 0; t < 8; t++) {
        acc1[t] = (f32x4)0.f; acc2[t] = (f32x4)0.f; acc3[t] = (f32x4)0.f;
    }
    #pragma unroll
    for (int kb = 0; kb < 4; kb++) {
        short8 av = *(const short8*)(aptr + kb * 32);
        #pragma unroll
        for (int t = 0; t < 8; t++) {
            const int widx = (kb * 8 + t) * 512 + lane * 8;
            short8 w1 = *(const short8*)(Wp1 + widx);
            short8 w2 = *(const short8*)(Wp2 + widx);
            short8 w3 = *(const short8*)(Wp3 + widx);
            acc1[t] = __builtin_amdgcn_mfma_f32_16x16x32_bf16(av, w1, acc1[t], 0, 0, 0);
            acc2[t] = __builtin_amdgcn_mfma_f32_16x16x32_bf16(av, w2, acc2[t], 0, 0, 0);
            acc3[t] = __builtin_amdgcn_mfma_f32_16x16x32_bf16(av, w3, acc3[t], 0, 0, 0);
        }
    }
    int grow[4]; bool ok[4]; float dg[4];
    #pragma unroll
    for (int i = 0; i < 4; i++) {
        grow[i] = row_base + kg * 4 + i;
        ok[i] = grow[i] < N_NODES;
        dg[i] = ok[i] ? degf[grow[i]] : 0.f;
    }
    #pragma unroll
    for (int t = 0; t < 8; t++) {
        const int c = t * 16 + r15;
        const float bb1 = b1v[c], bb3 = b3v[c];
        #pragma unroll
        for (int i = 0; i < 4; i++) {
            if (ok[i]) {
                size_t o = (size_t)grow[i] * HID + c;
                OUTb[o] = bf16_bits(dg[i] * (acc1[t][i] + bb1) + acc3[t][i] + bb3);
                Bb[o] = bf16_bits(acc2[t][i]);
            }
        }
    }
}

// ---------------- pool (mean of bf16 H) + FFN head ----------------

__global__ __launch_bounds__(128) void pool_ffn_kernel(const short* __restrict__ H,
                                                       const int* __restrict__ batch,
                                                       const float* __restrict__ Wf1,
                                                       const float* __restrict__ bf1,
                                                       const float* __restrict__ Wf2,
                                                       const float* __restrict__ bf2,
                                                       float* __restrict__ out) {
    const int g = blockIdx.x;
    const int t = threadIdx.x;  // 0..127

    int lo = 0, hi = N_NODES;
    while (lo < hi) { int mid = (lo + hi) >> 1; if (batch[mid] < g) lo = mid + 1; else hi = mid; }
    const int s = lo;
    hi = N_NODES;
    while (lo < hi) { int mid = (lo + hi) >> 1; if (batch[mid] < g + 1) lo = mid + 1; else hi = mid; }
    const int e = lo;

    float sum = 0.f;
    for (int n = s; n < e; n++) {
        short b = H[(size_t)n * HID + t];
        sum += __bfloat162float(*(__hip_bfloat16*)&b);
    }
    const float cntf = (float)(e - s);
    const float gx = sum / fmaxf(cntf, 1.f);

    __shared__ float lds[HID];
    lds[t] = gx;
    __syncthreads();

    float hsum = bf1[t];
    #pragma unroll 8
    for (int k = 0; k < HID; k++) hsum = fmaf(lds[k], Wf1[k * HID + t], hsum);
    const float hr = fmaxf(hsum, 0.f);

    float p0 = hr * Wf2[t * 2 + 0];
    float p1 = hr * Wf2[t * 2 + 1];
    #pragma unroll
    for (int off = 32; off > 0; off >>= 1) {
        p0 += __shfl_down(p0, off, 64);
        p1 += __shfl_down(p1, off, 64);
    }
    __shared__ float red[4];
    if ((t & 63) == 0) {
        red[(t >> 6) * 2 + 0] = p0;
        red[(t >> 6) * 2 + 1] = p1;
    }
    __syncthreads();
    if (t == 0) {
        out[g * 2 + 0] = red[0] + red[2] + bf2[0];
        out[g * 2 + 1] = red[1] + red[3] + bf2[1];
    }
}

// ---------------- launch ----------------

extern "C" void kernel_launch(void* const* d_in, const int* in_sizes, int n_in,
                              void* d_out, int out_size, void* d_ws, size_t ws_size,
                              hipStream_t stream) {
    (void)in_sizes; (void)n_in; (void)out_size; (void)ws_size;

    const float* x     = (const float*)d_in[0];
    const int*   ei    = (const int*)d_in[1];
    const int*   batch = (const int*)d_in[2];
    const float* W[9] = {
        (const float*)d_in[3],  (const float*)d_in[5],  (const float*)d_in[6],
        (const float*)d_in[8],  (const float*)d_in[10], (const float*)d_in[11],
        (const float*)d_in[13], (const float*)d_in[15], (const float*)d_in[16]};
    const float* b1_0 = (const float*)d_in[4];
    const float* b3_0 = (const float*)d_in[7];
    const float* b1_1 = (const float*)d_in[9];
    const float* b3_1 = (const float*)d_in[12];
    const float* b1_2 = (const float*)d_in[14];
    const float* b3_2 = (const float*)d_in[17];
    const float* Wf1  = (const float*)d_in[18];
    const float* bf1  = (const float*)d_in[19];
    const float* Wf2  = (const float*)d_in[20];
    const float* bf2  = (const float*)d_in[21];
    float* out = (float*)d_out;

    char* ws = (char*)d_ws;
    size_t off = 0;
    auto alloc = [&](size_t bytes) {
        void* p = ws + off;
        off += (bytes + 255) & ~(size_t)255;
        return p;
    };
    short* D0     = (short*)alloc((size_t)N_NODES * HID * 2);  // layer0 D; reused as OUT of gemm2
    short* E0     = (short*)alloc((size_t)N_NODES * HID * 2);  // layer0 E; reused as OUT of gemm1
    short* Bb_A   = (short*)alloc((size_t)N_NODES * HID * 2);
    short* Bb_B   = (short*)alloc((size_t)N_NODES * HID * 2);
    short* Hb     = (short*)alloc((size_t)N_NODES * HID * 2);
    float* degf   = (float*)alloc((size_t)N_NODES * 4);
    int*   rowptr = (int*)alloc((size_t)(N_NODES + 1) * 4);
    int*   cnt    = (int*)alloc((size_t)N_NODES * 4);
    int*   col    = (int*)alloc((size_t)N_EDGES * 4);
    int*   rank   = (int*)alloc((size_t)N_EDGES * 4);
    int*   partial= (int*)alloc((size_t)N_NODES * 4);
    int*   bsum   = (int*)alloc(1024);
    short* P[9];
    for (int m = 0; m < 9; m++) P[m] = (short*)alloc(16384 * 2);

    hipMemsetAsync(cnt, 0, (size_t)N_NODES * 4, stream);

    PackArgs pa;
    for (int m = 0; m < 9; m++) { pa.w[m] = W[m]; pa.o[m] = P[m]; }

    // pre-pack layer-0 weights (gemm0 in phase1 reads them)
    prepack_kernel<<<PREPACK_BLOCKS, 256, 0, stream>>>(pa);

    // phase 1 (interleaved): hist+rank (3/4 of blocks) || gemm0 || pack m3..8
    P1Args p1{ x, ei, cnt, rank, P[0], P[1], P[2], b1_0, b3_0, D0, E0, Bb_A, pa };
    phase1_kernel<<<P1_BLOCKS, 256, 0, stream>>>(p1);

    // scan
    const int NSB = (N_NODES + 1023) / 1024;  // 98
    scan_blocks<<<NSB, 1024, 0, stream>>>(cnt, partial, bsum);
    scan_finalize<<<NSB, 1024, 0, stream>>>(partial, bsum, cnt, rowptr, degf);

    // fill: scatter col (no atomics)
    fill_kernel<<<HIST_BLOCKS, 256, 0, stream>>>(ei, rank, rowptr, col);

    const int gather_grid = (N_NODES * 64 + 255) / 256;  // 25000

    // layer 0 gather: Hb = relu(deg*D0 + E0 - agg(Bb_A))
    gather0_kernel<<<gather_grid, 256, 0, stream>>>(rowptr, col, Bb_A, D0, E0, Hb);
    // layer 1 gemm: E0 <- OUT1, Bb_B
    leconv_mfma<<<GEMM_GRID, 256, 0, stream>>>(Hb, P[3], P[4], P[5], b1_1, b3_1, degf, Bb_B, E0);
    // layer 1 gather
    gatherL_kernel<<<gather_grid, 256, 0, stream>>>(rowptr, col, Bb_B, E0, Hb);
    // layer 2 gemm: D0 <- OUT2, Bb_A
    leconv_mfma<<<GEMM_GRID, 256, 0, stream>>>(Hb, P[6], P[7], P[8], b1_2, b3_2, degf, Bb_A, D0);
    // layer 2 gather
    gatherL_kernel<<<gather_grid, 256, 0, stream>>>(rowptr, col, Bb_A, D0, Hb);

    // pool + FFN
    pool_ffn_kernel<<<N_GRAPHS, 128, 0, stream>>>(Hb, batch, Wf1, bf1, Wf2, bf2, out);
}

// Round 13
// 472.641 us; speedup vs baseline: 1.2685x; 1.2685x over previous
//
#include <hip/hip_runtime.h>
#include <hip/hip_bf16.h>
#include <cstdint>

#define N_NODES 100000
#define N_EDGES 1600000
#define N_GRAPHS 2000
#define IN_DIM 37
#define HID 128

#define GEMM_GRID 1563      // 64-node tiles
#define HIST_BLOCKS 6250    // 1.6M / 256
#define PACK_BLOCKS 480     // (3*8192 + 6*16384) / 256

typedef __attribute__((ext_vector_type(8))) short short8;
typedef __attribute__((ext_vector_type(4))) float f32x4;

static __device__ __forceinline__ short bf16_bits(float f) {
    __hip_bfloat16 h = __float2bfloat16(f);
    return *reinterpret_cast<short*>(&h);
}
static __device__ __forceinline__ float bf16_lo(uint32_t u) {
    uint32_t v = u << 16;
    return *reinterpret_cast<float*>(&v);
}
static __device__ __forceinline__ float bf16_hi(uint32_t u) {
    uint32_t v = u & 0xffff0000u;
    return *reinterpret_cast<float*>(&v);
}
static __device__ __forceinline__ uint32_t pack_bf16(float lo, float hi) {
    return ((uint32_t)(uint16_t)bf16_bits(hi) << 16) | (uint16_t)bf16_bits(lo);
}

// ---------------- weight pack ----------------

struct PackArgs {
    const float* w[9];
    short* o[9];
};

static __device__ __forceinline__ void pack_one(const PackArgs& pa, int m, int r, int kin) {
    const int i = r & 7, lane = (r >> 3) & 63, t = (r >> 9) & 7, kb = r >> 12;
    const int k = kb * 32 + (lane >> 4) * 8 + i;
    const int c = t * 16 + (lane & 15);
    float v = (k < kin) ? pa.w[m][(size_t)k * HID + c] : 0.f;
    pa.o[m][r] = bf16_bits(v);
}

// ---------------- phase 1: hist(+rank, the ONLY atomic pass) || pack all 9 ----------------

__global__ __launch_bounds__(256) void phase1_kernel(const int* __restrict__ ei,
                                                     int* __restrict__ cnt,
                                                     int* __restrict__ rank,
                                                     PackArgs pa) {
    const int b = blockIdx.x;
    if (b < HIST_BLOCKS) {
        const int e = b * 256 + threadIdx.x;
        const int d = ei[N_EDGES + e];
        rank[e] = atomicAdd(&cnt[d], 1);
        return;
    }
    const int idx = (b - HIST_BLOCKS) * 256 + threadIdx.x;  // < 122880
    if (idx < 24576) pack_one(pa, idx >> 13, idx & 8191, IN_DIM);
    else { const int q = idx - 24576; pack_one(pa, 3 + (q >> 14), q & 16383, HID); }
}

// ---------------- scan: cnt -> rowptr (+degf) ----------------

__global__ __launch_bounds__(1024) void scan_blocks(const int* __restrict__ cnt,
                                                    int* __restrict__ partial,
                                                    int* __restrict__ bsum) {
    __shared__ int ws[16];
    const int tid = threadIdx.x, lane = tid & 63, wv = tid >> 6;
    const int i = blockIdx.x * 1024 + tid;
    int v0 = (i < N_NODES) ? cnt[i] : 0;
    int v = v0;
    #pragma unroll
    for (int off = 1; off < 64; off <<= 1) {
        int n = __shfl_up(v, off, 64);
        if (lane >= off) v += n;
    }
    if (lane == 63) ws[wv] = v;
    __syncthreads();
    int woff = 0, tot = 0;
    #pragma unroll
    for (int w = 0; w < 16; w++) {
        int s = ws[w];
        if (w < wv) woff += s;
        tot += s;
    }
    if (i < N_NODES) partial[i] = woff + v - v0;
    if (tid == 0) bsum[blockIdx.x] = tot;
}

__global__ __launch_bounds__(1024) void scan_finalize(const int* __restrict__ partial,
                                                      const int* __restrict__ bsum,
                                                      const int* __restrict__ cnt,
                                                      int* __restrict__ rowptr,
                                                      float* __restrict__ degf) {
    __shared__ int off_s;
    const int tid = threadIdx.x, b = blockIdx.x;
    if (tid < 64) {
        int acc = 0;
        for (int j = tid; j < b; j += 64) acc += bsum[j];
        #pragma unroll
        for (int off = 32; off; off >>= 1) acc += __shfl_down(acc, off, 64);
        if (tid == 0) off_s = acc;
    }
    __syncthreads();
    const int i = b * 1024 + tid;
    if (i < N_NODES) {
        rowptr[i] = off_s + partial[i];
        degf[i] = (float)cnt[i];
    }
    if (b == 0 && tid == 0) rowptr[N_NODES] = N_EDGES;
}

// ---------------- layer-0 GEMM from fp32 x (K=64 padded), non-swapped epilogue ----------------
// D0 = bf16(x@W1 + b1), E0 = bf16(x@W3 + b3), Bb = bf16(x@W2)

static __device__ __forceinline__ void gemm0_body(
    int blk, const float* __restrict__ x,
    const short* __restrict__ Wp1, const short* __restrict__ Wp2, const short* __restrict__ Wp3,
    const float* __restrict__ b1v, const float* __restrict__ b3v,
    short* __restrict__ D0, short* __restrict__ E0, short* __restrict__ Bb) {
    const int tid = threadIdx.x;
    const int wave = tid >> 6, lane = tid & 63;
    const int row_base = blk * 64 + wave * 16;
    const int r15 = lane & 15, kg = lane >> 4;
    int arow = row_base + r15;
    if (arow >= N_NODES) arow = N_NODES - 1;
    const float* xr = x + (size_t)arow * IN_DIM;

    f32x4 acc1[8], acc2[8], acc3[8];
    #pragma unroll
    for (int t = 0; t < 8; t++) {
        acc1[t] = (f32x4)0.f; acc2[t] = (f32x4)0.f; acc3[t] = (f32x4)0.f;
    }
    #pragma unroll
    for (int kb = 0; kb < 2; kb++) {
        short8 av;
        #pragma unroll
        for (int i = 0; i < 8; i++) {
            const int k = kb * 32 + kg * 8 + i;
            av[i] = (k < IN_DIM) ? bf16_bits(xr[k]) : (short)0;
        }
        #pragma unroll
        for (int t = 0; t < 8; t++) {
            const int widx = (kb * 8 + t) * 512 + lane * 8;
            short8 w1 = *(const short8*)(Wp1 + widx);
            short8 w2 = *(const short8*)(Wp2 + widx);
            short8 w3 = *(const short8*)(Wp3 + widx);
            acc1[t] = __builtin_amdgcn_mfma_f32_16x16x32_bf16(av, w1, acc1[t], 0, 0, 0);
            acc2[t] = __builtin_amdgcn_mfma_f32_16x16x32_bf16(av, w2, acc2[t], 0, 0, 0);
            acc3[t] = __builtin_amdgcn_mfma_f32_16x16x32_bf16(av, w3, acc3[t], 0, 0, 0);
        }
    }
    int grow[4]; bool ok[4];
    #pragma unroll
    for (int i = 0; i < 4; i++) {
        grow[i] = row_base + kg * 4 + i;
        ok[i] = grow[i] < N_NODES;
    }
    #pragma unroll
    for (int t = 0; t < 8; t++) {
        const int c = t * 16 + r15;
        const float bb1 = b1v[c], bb3 = b3v[c];
        #pragma unroll
        for (int i = 0; i < 4; i++) {
            if (ok[i]) {
                size_t o = (size_t)grow[i] * HID + c;
                D0[o] = bf16_bits(acc1[t][i] + bb1);
                E0[o] = bf16_bits(acc3[t][i] + bb3);
                Bb[o] = bf16_bits(acc2[t][i]);
            }
        }
    }
}

// ---------------- fill || gemm0 (R5-measured overlap pattern, non-swapped) ----------------

__global__ __launch_bounds__(256) void fill_gemm0_kernel(
    const int* __restrict__ ei, const int* __restrict__ rank, const int* __restrict__ rowptr,
    int* __restrict__ col,
    const float* __restrict__ x,
    const short* __restrict__ Wp1, const short* __restrict__ Wp2, const short* __restrict__ Wp3,
    const float* __restrict__ b1v, const float* __restrict__ b3v,
    short* __restrict__ D0, short* __restrict__ E0, short* __restrict__ Bb) {
    const int b = blockIdx.x;
    if (b < HIST_BLOCKS) {
        const int e = b * 256 + threadIdx.x;
        const int s = ei[e];
        const int d = ei[N_EDGES + e];
        col[rowptr[d] + rank[e]] = s;
        return;
    }
    gemm0_body(b - HIST_BLOCKS, x, Wp1, Wp2, Wp3, b1v, b3v, D0, E0, Bb);
}

// ---------------- gather core: 4 edges/wave-iter, 16B/lane, col prefetch+shuffle ----------------

static __device__ __forceinline__ void agg_edges4(const int* __restrict__ col, int s, int e,
                                                  const short* __restrict__ Bb,
                                                  int lane, int grp, int l16, float* acc) {
    for (int base = s; base < e; base += 64) {
        const int cnt = min(64, e - base);
        const int ci = base + lane;
        const int cv = col[(ci < e) ? ci : (e - 1)];
        for (int t = 0; t < cnt; t += 4) {
            const int idx = t + grp;
            const bool on = idx < cnt;
            const float w = on ? 1.f : 0.f;
            const int c = __shfl(cv, on ? idx : 0, 64);
            const uint4 u = *(const uint4*)(Bb + (size_t)c * HID + l16 * 8);
            acc[0] = fmaf(w, bf16_lo(u.x), acc[0]);
            acc[1] = fmaf(w, bf16_hi(u.x), acc[1]);
            acc[2] = fmaf(w, bf16_lo(u.y), acc[2]);
            acc[3] = fmaf(w, bf16_hi(u.y), acc[3]);
            acc[4] = fmaf(w, bf16_lo(u.z), acc[4]);
            acc[5] = fmaf(w, bf16_hi(u.z), acc[5]);
            acc[6] = fmaf(w, bf16_lo(u.w), acc[6]);
            acc[7] = fmaf(w, bf16_hi(u.w), acc[7]);
        }
    }
    #pragma unroll
    for (int j = 0; j < 8; j++) {
        acc[j] += __shfl_xor(acc[j], 16, 64);
        acc[j] += __shfl_xor(acc[j], 32, 64);
    }
}

// layer-0 gather: Hb = bf16(relu(deg*D0 - agg + E0))
__global__ __launch_bounds__(256) void gather0_kernel(const int* __restrict__ rowptr,
                                                      const int* __restrict__ col,
                                                      const short* __restrict__ Bb,
                                                      const short* __restrict__ D0,
                                                      const short* __restrict__ E0,
                                                      short* __restrict__ Hb) {
    const int wid = (blockIdx.x * 256 + threadIdx.x) >> 6;
    if (wid >= N_NODES) return;
    const int lane = threadIdx.x & 63, grp = lane >> 4, l16 = lane & 15;
    const int s = rowptr[wid], e = rowptr[wid + 1];
    float acc[8] = {0.f, 0.f, 0.f, 0.f, 0.f, 0.f, 0.f, 0.f};
    agg_edges4(col, s, e, Bb, lane, grp, l16, acc);
    if (grp == 0) {
        const float dg = (float)(e - s);
        const uint4 ud = *(const uint4*)(D0 + (size_t)wid * HID + l16 * 8);
        const uint4 ue = *(const uint4*)(E0 + (size_t)wid * HID + l16 * 8);
        uint4 r;
        r.x = pack_bf16(fmaxf(fmaf(dg, bf16_lo(ud.x), bf16_lo(ue.x)) - acc[0], 0.f),
                        fmaxf(fmaf(dg, bf16_hi(ud.x), bf16_hi(ue.x)) - acc[1], 0.f));
        r.y = pack_bf16(fmaxf(fmaf(dg, bf16_lo(ud.y), bf16_lo(ue.y)) - acc[2], 0.f),
                        fmaxf(fmaf(dg, bf16_hi(ud.y), bf16_hi(ue.y)) - acc[3], 0.f));
        r.z = pack_bf16(fmaxf(fmaf(dg, bf16_lo(ud.z), bf16_lo(ue.z)) - acc[4], 0.f),
                        fmaxf(fmaf(dg, bf16_hi(ud.z), bf16_hi(ue.z)) - acc[5], 0.f));
        r.w = pack_bf16(fmaxf(fmaf(dg, bf16_lo(ud.w), bf16_lo(ue.w)) - acc[6], 0.f),
                        fmaxf(fmaf(dg, bf16_hi(ud.w), bf16_hi(ue.w)) - acc[7], 0.f));
        *(uint4*)(Hb + (size_t)wid * HID + l16 * 8) = r;
    }
}

// layers 1/2 gather: Hb = bf16(relu(OUT - agg)), deg applied in gemm
__global__ __launch_bounds__(256) void gatherL_kernel(const int* __restrict__ rowptr,
                                                      const int* __restrict__ col,
                                                      const short* __restrict__ Bb,
                                                      const short* __restrict__ OUTb,
                                                      short* __restrict__ Hb) {
    const int wid = (blockIdx.x * 256 + threadIdx.x) >> 6;
    if (wid >= N_NODES) return;
    const int lane = threadIdx.x & 63, grp = lane >> 4, l16 = lane & 15;
    const int s = rowptr[wid], e = rowptr[wid + 1];
    float acc[8] = {0.f, 0.f, 0.f, 0.f, 0.f, 0.f, 0.f, 0.f};
    agg_edges4(col, s, e, Bb, lane, grp, l16, acc);
    if (grp == 0) {
        const uint4 uo = *(const uint4*)(OUTb + (size_t)wid * HID + l16 * 8);
        uint4 r;
        r.x = pack_bf16(fmaxf(bf16_lo(uo.x) - acc[0], 0.f), fmaxf(bf16_hi(uo.x) - acc[1], 0.f));
        r.y = pack_bf16(fmaxf(bf16_lo(uo.y) - acc[2], 0.f), fmaxf(bf16_hi(uo.y) - acc[3], 0.f));
        r.z = pack_bf16(fmaxf(bf16_lo(uo.z) - acc[4], 0.f), fmaxf(bf16_hi(uo.z) - acc[5], 0.f));
        r.w = pack_bf16(fmaxf(bf16_lo(uo.w) - acc[6], 0.f), fmaxf(bf16_hi(uo.w) - acc[7], 0.f));
        *(uint4*)(Hb + (size_t)wid * HID + l16 * 8) = r;
    }
}

// ---------------- layers 1/2 GEMM (non-swapped): OUT = bf16(deg*(h@W1+b1)+h@W3+b3), Bb = bf16(h@W2) ----------------

__global__ __launch_bounds__(256) void leconv_mfma(
    const short* __restrict__ Hb,
    const short* __restrict__ Wp1, const short* __restrict__ Wp2, const short* __restrict__ Wp3,
    const float* __restrict__ b1v, const float* __restrict__ b3v,
    const float* __restrict__ degf,
    short* __restrict__ Bb, short* __restrict__ OUTb) {
    const int tid = threadIdx.x;
    const int wave = tid >> 6, lane = tid & 63;
    const int row_base = blockIdx.x * 64 + wave * 16;
    const int r15 = lane & 15, kg = lane >> 4;
    int arow = row_base + r15;
    if (arow >= N_NODES) arow = N_NODES - 1;
    const short* aptr = Hb + (size_t)arow * HID + kg * 8;

    f32x4 acc1[8], acc2[8], acc3[8];
    #pragma unroll
    for (int t = 0; t < 8; t++) {
        acc1[t] = (f32x4)0.f; acc2[t] = (f32x4)0.f; acc3[t] = (f32x4)0.f;
    }
    #pragma unroll
    for (int kb = 0; kb < 4; kb++) {
        short8 av = *(const short8*)(aptr + kb * 32);
        #pragma unroll
        for (int t = 0; t < 8; t++) {
            const int widx = (kb * 8 + t) * 512 + lane * 8;
            short8 w1 = *(const short8*)(Wp1 + widx);
            short8 w2 = *(const short8*)(Wp2 + widx);
            short8 w3 = *(const short8*)(Wp3 + widx);
            acc1[t] = __builtin_amdgcn_mfma_f32_16x16x32_bf16(av, w1, acc1[t], 0, 0, 0);
            acc2[t] = __builtin_amdgcn_mfma_f32_16x16x32_bf16(av, w2, acc2[t], 0, 0, 0);
            acc3[t] = __builtin_amdgcn_mfma_f32_16x16x32_bf16(av, w3, acc3[t], 0, 0, 0);
        }
    }
    int grow[4]; bool ok[4]; float dg[4];
    #pragma unroll
    for (int i = 0; i < 4; i++) {
        grow[i] = row_base + kg * 4 + i;
        ok[i] = grow[i] < N_NODES;
        dg[i] = ok[i] ? degf[grow[i]] : 0.f;
    }
    #pragma unroll
    for (int t = 0; t < 8; t++) {
        const int c = t * 16 + r15;
        const float bb1 = b1v[c], bb3 = b3v[c];
        #pragma unroll
        for (int i = 0; i < 4; i++) {
            if (ok[i]) {
                size_t o = (size_t)grow[i] * HID + c;
                OUTb[o] = bf16_bits(dg[i] * (acc1[t][i] + bb1) + acc3[t][i] + bb3);
                Bb[o] = bf16_bits(acc2[t][i]);
            }
        }
    }
}

// ---------------- pool (mean of bf16 H) + FFN head ----------------

__global__ __launch_bounds__(128) void pool_ffn_kernel(const short* __restrict__ H,
                                                       const int* __restrict__ batch,
                                                       const float* __restrict__ Wf1,
                                                       const float* __restrict__ bf1,
                                                       const float* __restrict__ Wf2,
                                                       const float* __restrict__ bf2,
                                                       float* __restrict__ out) {
    const int g = blockIdx.x;
    const int t = threadIdx.x;  // 0..127

    int lo = 0, hi = N_NODES;
    while (lo < hi) { int mid = (lo + hi) >> 1; if (batch[mid] < g) lo = mid + 1; else hi = mid; }
    const int s = lo;
    hi = N_NODES;
    while (lo < hi) { int mid = (lo + hi) >> 1; if (batch[mid] < g + 1) lo = mid + 1; else hi = mid; }
    const int e = lo;

    float sum = 0.f;
    for (int n = s; n < e; n++) {
        short b = H[(size_t)n * HID + t];
        sum += __bfloat162float(*(__hip_bfloat16*)&b);
    }
    const float cntf = (float)(e - s);
    const float gx = sum / fmaxf(cntf, 1.f);

    __shared__ float lds[HID];
    lds[t] = gx;
    __syncthreads();

    float hsum = bf1[t];
    #pragma unroll 8
    for (int k = 0; k < HID; k++) hsum = fmaf(lds[k], Wf1[k * HID + t], hsum);
    const float hr = fmaxf(hsum, 0.f);

    float p0 = hr * Wf2[t * 2 + 0];
    float p1 = hr * Wf2[t * 2 + 1];
    #pragma unroll
    for (int off = 32; off > 0; off >>= 1) {
        p0 += __shfl_down(p0, off, 64);
        p1 += __shfl_down(p1, off, 64);
    }
    __shared__ float red[4];
    if ((t & 63) == 0) {
        red[(t >> 6) * 2 + 0] = p0;
        red[(t >> 6) * 2 + 1] = p1;
    }
    __syncthreads();
    if (t == 0) {
        out[g * 2 + 0] = red[0] + red[2] + bf2[0];
        out[g * 2 + 1] = red[1] + red[3] + bf2[1];
    }
}

// ---------------- launch ----------------

extern "C" void kernel_launch(void* const* d_in, const int* in_sizes, int n_in,
                              void* d_out, int out_size, void* d_ws, size_t ws_size,
                              hipStream_t stream) {
    (void)in_sizes; (void)n_in; (void)out_size; (void)ws_size;

    const float* x     = (const float*)d_in[0];
    const int*   ei    = (const int*)d_in[1];
    const int*   batch = (const int*)d_in[2];
    const float* W[9] = {
        (const float*)d_in[3],  (const float*)d_in[5],  (const float*)d_in[6],
        (const float*)d_in[8],  (const float*)d_in[10], (const float*)d_in[11],
        (const float*)d_in[13], (const float*)d_in[15], (const float*)d_in[16]};
    const float* b1_0 = (const float*)d_in[4];
    const float* b3_0 = (const float*)d_in[7];
    const float* b1_1 = (const float*)d_in[9];
    const float* b3_1 = (const float*)d_in[12];
    const float* b1_2 = (const float*)d_in[14];
    const float* b3_2 = (const float*)d_in[17];
    const float* Wf1  = (const float*)d_in[18];
    const float* bf1  = (const float*)d_in[19];
    const float* Wf2  = (const float*)d_in[20];
    const float* bf2  = (const float*)d_in[21];
    float* out = (float*)d_out;

    char* ws = (char*)d_ws;
    size_t off = 0;
    auto alloc = [&](size_t bytes) {
        void* p = ws + off;
        off += (bytes + 255) & ~(size_t)255;
        return p;
    };
    short* D0     = (short*)alloc((size_t)N_NODES * HID * 2);  // layer0 D; reused as OUT of gemm2
    short* E0     = (short*)alloc((size_t)N_NODES * HID * 2);  // layer0 E; reused as OUT of gemm1
    short* Bb_A   = (short*)alloc((size_t)N_NODES * HID * 2);
    short* Bb_B   = (short*)alloc((size_t)N_NODES * HID * 2);
    short* Hb     = (short*)alloc((size_t)N_NODES * HID * 2);
    float* degf   = (float*)alloc((size_t)N_NODES * 4);
    int*   rowptr = (int*)alloc((size_t)(N_NODES + 1) * 4);
    int*   cnt    = (int*)alloc((size_t)N_NODES * 4);
    int*   col    = (int*)alloc((size_t)N_EDGES * 4);
    int*   rank   = (int*)alloc((size_t)N_EDGES * 4);
    int*   partial= (int*)alloc((size_t)N_NODES * 4);
    int*   bsum   = (int*)alloc(1024);
    short* P[9];
    for (int m = 0; m < 9; m++) P[m] = (short*)alloc(16384 * 2);

    hipMemsetAsync(cnt, 0, (size_t)N_NODES * 4, stream);

    PackArgs pa;
    for (int m = 0; m < 9; m++) { pa.w[m] = W[m]; pa.o[m] = P[m]; }

    // phase 1: hist+rank || pack all 9 (measured ~77 us)
    phase1_kernel<<<HIST_BLOCKS + PACK_BLOCKS, 256, 0, stream>>>(ei, cnt, rank, pa);

    // scan
    const int NSB = (N_NODES + 1023) / 1024;  // 98
    scan_blocks<<<NSB, 1024, 0, stream>>>(cnt, partial, bsum);
    scan_finalize<<<NSB, 1024, 0, stream>>>(partial, bsum, cnt, rowptr, degf);

    // fill || gemm0 -> D0, E0, Bb_A (measured-good overlap; non-swapped epilogue)
    fill_gemm0_kernel<<<HIST_BLOCKS + GEMM_GRID, 256, 0, stream>>>(
        ei, rank, rowptr, col, x, P[0], P[1], P[2], b1_0, b3_0, D0, E0, Bb_A);

    const int gather_grid = (N_NODES * 64 + 255) / 256;  // 25000

    // layer 0 gather: Hb = relu(deg*D0 + E0 - agg(Bb_A))
    gather0_kernel<<<gather_grid, 256, 0, stream>>>(rowptr, col, Bb_A, D0, E0, Hb);
    // layer 1 gemm: E0 <- OUT1, Bb_B
    leconv_mfma<<<GEMM_GRID, 256, 0, stream>>>(Hb, P[3], P[4], P[5], b1_1, b3_1, degf, Bb_B, E0);
    // layer 1 gather
    gatherL_kernel<<<gather_grid, 256, 0, stream>>>(rowptr, col, Bb_B, E0, Hb);
    // layer 2 gemm: D0 <- OUT2, Bb_A
    leconv_mfma<<<GEMM_GRID, 256, 0, stream>>>(Hb, P[6], P[7], P[8], b1_2, b3_2, degf, Bb_A, D0);
    // layer 2 gather
    gatherL_kernel<<<gather_grid, 256, 0, stream>>>(rowptr, col, Bb_A, D0, Hb);

    // pool + FFN
    pool_ffn_kernel<<<N_GRAPHS, 128, 0, stream>>>(Hb, batch, Wf1, bf1, Wf2, bf2, out);
}